// Round 4
// baseline (1193.785 us; speedup 1.0000x reference)
//
#include <hip/hip_runtime.h>

// Problem constants (from reference setup_inputs)
#define B_  16
#define T_  4096
#define C_  512
#define K_  4

// ---------------- single-pass lookback kernel geometry ----------------
#define NTL 128                 // chunks along T
#define LL  (T_ / NTL)          // 32 timesteps per chunk
// ws layout (floats): [0]=ticket counter (int), ints 16.. : flags[B_*NTL],
// byte 65536: part[B_*NTL*K_*C_], then incl[same]
#define WS_FLAGS_OFF   16
#define WS_PART_OFF    (65536 / 4)
#define WS_STATE_FLTS  (B_ * NTL * K_ * C_)            // 4,194,304 floats = 16 MiB
#define WS_INCL_OFF    (WS_PART_OFF + WS_STATE_FLTS)
#define WS_NEEDED_BYTES ((size_t)65536 + 2ull * WS_STATE_FLTS * 4)

// ---------------- fallback 3-pass geometry ----------------
#define NT_ 64
#define L_  (T_ / NT_)
#define C4_ (C_ / 4)

typedef float nfloat4 __attribute__((ext_vector_type(4)));

__device__ __forceinline__ float sigmoid_clamp(float la) {
    float av = 1.0f / (1.0f + expf(-la));
    return fminf(fmaxf(av, 1e-4f), 1.0f - 1e-4f);
}

// ======================================================================
// Single-pass decoupled-lookback scan.
// Block = one (b, chunk j). 512 threads, thread = channel c.
// Chunk x (32 t x 512 c = 64 KiB) lives in dynamic LDS for both scans.
// ======================================================================
__global__ __launch_bounds__(512, 4) void ema_lookback(
    const float* __restrict__ x,
    const float* __restrict__ logit_alpha,
    const float* __restrict__ mix_logits,
    float* __restrict__ ws,
    float* __restrict__ out)
{
    extern __shared__ float lx[];                 // LL*C_ floats + 4 broadcast slot
    int* sb = (int*)&lx[LL * C_];                 // block-uniform broadcast slot

    const int tid = threadIdx.x;
    int* wsi = (int*)ws;

    // ticket = actual scheduling order -> deadlock-free lookback
    if (tid == 0) sb[0] = atomicAdd(&wsi[0], 1);
    __syncthreads();
    const int ticket = sb[0];
    const int b = ticket & (B_ - 1);
    const int j = ticket >> 4;                    // 0..NTL-1
    const int c = tid;

    // stage x chunk -> LDS (float4, coalesced)
    {
        const float4* xg = (const float4*)(x + ((size_t)b * T_ + (size_t)j * LL) * C_);
        float4* l4 = (float4*)lx;
#pragma unroll
        for (int i = 0; i < (LL * C_ / 4) / 512; ++i)
            l4[i * 512 + tid] = xg[i * 512 + tid];
    }

    // per-thread params
    float a[K_], oma[K_], A[K_], s[K_];
#pragma unroll
    for (int k = 0; k < K_; ++k) {
        float av = sigmoid_clamp(logit_alpha[k * C_ + c]);
        a[k] = av; oma[k] = 1.0f - av;
        float p = av;
#pragma unroll
        for (int q = 0; q < 5; ++q) p *= p;       // A = a^32 = a^LL
        A[k] = p; s[k] = 0.0f;
    }

    __syncthreads();                              // LDS staged

    // zero-init partial scan over the chunk
    for (int t = 0; t < LL; ++t) {
        float xv = lx[t * C_ + c];
#pragma unroll
        for (int k = 0; k < K_; ++k) s[k] = fmaf(a[k], s[k], oma[k] * xv);
    }

    float* part = ws + WS_PART_OFF;
    float* incl = ws + WS_INCL_OFF;
    const size_t pbase = ((size_t)(b * NTL + j) * K_) * C_ + c;

    // publish partial (flag=1)
#pragma unroll
    for (int k = 0; k < K_; ++k) part[pbase + (size_t)k * C_] = s[k];
    __threadfence();
    __syncthreads();
    if (tid == 0)
        __hip_atomic_store(&wsi[WS_FLAGS_OFF + b * NTL + j], 1,
                           __ATOMIC_RELEASE, __HIP_MEMORY_SCOPE_AGENT);

    // lookback: carry = I_{j-1} = sum_{d<j} A^{j-1-d} s_d + A^j x0
    float acc[K_] = {0.f, 0.f, 0.f, 0.f};
    float w[K_]   = {1.f, 1.f, 1.f, 1.f};
    for (int d = j - 1; ; --d) {
        if (d < 0) {
            float x0 = x[(size_t)b * T_ * C_ + c];
#pragma unroll
            for (int k = 0; k < K_; ++k) acc[k] = fmaf(w[k], x0, acc[k]);
            break;
        }
        if (tid == 0) {
            int f;
            do {
                f = __hip_atomic_load(&wsi[WS_FLAGS_OFF + b * NTL + d],
                                      __ATOMIC_ACQUIRE, __HIP_MEMORY_SCOPE_AGENT);
                if (f == 0) __builtin_amdgcn_s_sleep(4);
            } while (f == 0);
            sb[0] = f;
        }
        __syncthreads();
        const int f = sb[0];
        __syncthreads();
        const float* src = (f == 2 ? incl : part) + ((size_t)(b * NTL + d) * K_) * C_ + c;
#pragma unroll
        for (int k = 0; k < K_; ++k) acc[k] = fmaf(w[k], src[(size_t)k * C_], acc[k]);
        if (f == 2) break;                        // hit an inclusive carry
#pragma unroll
        for (int k = 0; k < K_; ++k) w[k] *= A[k];
    }

    // publish inclusive I_j = A*carry + s (flag=2)
#pragma unroll
    for (int k = 0; k < K_; ++k) incl[pbase + (size_t)k * C_] = fmaf(A[k], acc[k], s[k]);
    __threadfence();
    __syncthreads();
    if (tid == 0)
        __hip_atomic_store(&wsi[WS_FLAGS_OFF + b * NTL + j], 2,
                           __ATOMIC_RELEASE, __HIP_MEMORY_SCOPE_AGENT);

    // softmax mix weights (mix_logits[c][0..K) contiguous -> one float4)
    float m[K_];
    {
        float4 ml = ((const float4*)mix_logits)[c];
        float mx = fmaxf(fmaxf(ml.x, ml.y), fmaxf(ml.z, ml.w));
        float e0 = expf(ml.x - mx), e1 = expf(ml.y - mx);
        float e2 = expf(ml.z - mx), e3 = expf(ml.w - mx);
        float inv = 1.0f / (e0 + e1 + e2 + e3);
        m[0] = e0 * inv; m[1] = e1 * inv; m[2] = e2 * inv; m[3] = e3 * inv;
    }

    // rescan from carry, mix, nontemporal write
    float y[K_];
#pragma unroll
    for (int k = 0; k < K_; ++k) y[k] = acc[k];
    float* op = out + ((size_t)b * T_ + (size_t)j * LL) * C_ + c;
    for (int t = 0; t < LL; ++t) {
        float xv = lx[t * C_ + c];
        float o = 0.0f;
#pragma unroll
        for (int k = 0; k < K_; ++k) {
            y[k] = fmaf(a[k], y[k], oma[k] * xv);
            o = fmaf(m[k], y[k], o);
        }
        __builtin_nontemporal_store(o, op + (size_t)t * C_);
    }
}

// ======================================================================
// Fallback 3-pass (proven R1 path) — used if ws_size is too small.
// ======================================================================
__global__ __launch_bounds__(256) void ema_pass1(const float4* __restrict__ x4,
                                                 const float* __restrict__ logit_alpha,
                                                 float4* __restrict__ ws4) {
    const int c4 = threadIdx.x & (C4_ - 1);
    const int jh = threadIdx.x >> 7;
    const int b  = blockIdx.x / (NT_ / 2);
    const int j  = (blockIdx.x % (NT_ / 2)) * 2 + jh;

    float4 a[K_], oma[K_], s[K_];
#pragma unroll
    for (int k = 0; k < K_; ++k) {
        float4 la = ((const float4*)logit_alpha)[k * C4_ + c4];
        a[k].x = sigmoid_clamp(la.x); a[k].y = sigmoid_clamp(la.y);
        a[k].z = sigmoid_clamp(la.z); a[k].w = sigmoid_clamp(la.w);
        oma[k].x = 1.0f - a[k].x; oma[k].y = 1.0f - a[k].y;
        oma[k].z = 1.0f - a[k].z; oma[k].w = 1.0f - a[k].w;
        s[k].x = s[k].y = s[k].z = s[k].w = 0.0f;
    }
    const float4* xp = x4 + ((size_t)b * T_ + (size_t)j * L_) * C4_ + c4;
#pragma unroll 4
    for (int i = 0; i < L_; ++i) {
        float4 xv = xp[(size_t)i * C4_];
#pragma unroll
        for (int k = 0; k < K_; ++k) {
            s[k].x = fmaf(a[k].x, s[k].x, oma[k].x * xv.x);
            s[k].y = fmaf(a[k].y, s[k].y, oma[k].y * xv.y);
            s[k].z = fmaf(a[k].z, s[k].z, oma[k].z * xv.z);
            s[k].w = fmaf(a[k].w, s[k].w, oma[k].w * xv.w);
        }
    }
#pragma unroll
    for (int k = 0; k < K_; ++k)
        ws4[(((size_t)b * K_ + k) * NT_ + j) * C4_ + c4] = s[k];
}

__global__ __launch_bounds__(128) void ema_pass2(const float* __restrict__ x,
                                                 const float* __restrict__ logit_alpha,
                                                 float* __restrict__ ws) {
    const int ct = blockIdx.x & 3;
    const int bk = blockIdx.x >> 2;
    const int b  = bk / K_;
    const int k  = bk % K_;
    const int c  = ct * 128 + threadIdx.x;

    float av = sigmoid_clamp(logit_alpha[k * C_ + c]);
    float A = av;
#pragma unroll
    for (int q = 0; q < 6; ++q) A *= A;

    float carry = x[(size_t)b * T_ * C_ + c];
    float* wsb = ws + ((size_t)b * K_ + k) * NT_ * C_ + c;
    for (int j = 0; j < NT_; ++j) {
        float sj = wsb[(size_t)j * C_];
        wsb[(size_t)j * C_] = carry;
        carry = fmaf(A, carry, sj);
    }
}

__global__ __launch_bounds__(256) void ema_pass3(const float4* __restrict__ x4,
                                                 const float* __restrict__ logit_alpha,
                                                 const float4* __restrict__ ml4,
                                                 const float4* __restrict__ ws4,
                                                 float4* __restrict__ out4) {
    const int c4 = threadIdx.x & (C4_ - 1);
    const int jh = threadIdx.x >> 7;
    const int b  = blockIdx.x / (NT_ / 2);
    const int j  = (blockIdx.x % (NT_ / 2)) * 2 + jh;

    float4 a[K_], oma[K_], y[K_];
    float  m[K_][4];
#pragma unroll
    for (int k = 0; k < K_; ++k) {
        float4 la = ((const float4*)logit_alpha)[k * C4_ + c4];
        a[k].x = sigmoid_clamp(la.x); a[k].y = sigmoid_clamp(la.y);
        a[k].z = sigmoid_clamp(la.z); a[k].w = sigmoid_clamp(la.w);
        oma[k].x = 1.0f - a[k].x; oma[k].y = 1.0f - a[k].y;
        oma[k].z = 1.0f - a[k].z; oma[k].w = 1.0f - a[k].w;
        y[k] = ws4[(((size_t)b * K_ + k) * NT_ + j) * C4_ + c4];
    }
#pragma unroll
    for (int ci = 0; ci < 4; ++ci) {
        float4 ml = ml4[(size_t)c4 * 4 + ci];
        float mx = fmaxf(fmaxf(ml.x, ml.y), fmaxf(ml.z, ml.w));
        float e0 = expf(ml.x - mx), e1 = expf(ml.y - mx);
        float e2 = expf(ml.z - mx), e3 = expf(ml.w - mx);
        float inv = 1.0f / (e0 + e1 + e2 + e3);
        m[0][ci] = e0 * inv; m[1][ci] = e1 * inv;
        m[2][ci] = e2 * inv; m[3][ci] = e3 * inv;
    }
    const float4* xp = x4   + ((size_t)b * T_ + (size_t)j * L_) * C4_ + c4;
    float4*       op = out4 + ((size_t)b * T_ + (size_t)j * L_) * C4_ + c4;
#pragma unroll 4
    for (int i = 0; i < L_; ++i) {
        float4 xv = xp[(size_t)i * C4_];
        float4 acc; acc.x = acc.y = acc.z = acc.w = 0.0f;
#pragma unroll
        for (int k = 0; k < K_; ++k) {
            y[k].x = fmaf(a[k].x, y[k].x, oma[k].x * xv.x);
            y[k].y = fmaf(a[k].y, y[k].y, oma[k].y * xv.y);
            y[k].z = fmaf(a[k].z, y[k].z, oma[k].z * xv.z);
            y[k].w = fmaf(a[k].w, y[k].w, oma[k].w * xv.w);
            acc.x = fmaf(m[k][0], y[k].x, acc.x);
            acc.y = fmaf(m[k][1], y[k].y, acc.y);
            acc.z = fmaf(m[k][2], y[k].z, acc.z);
            acc.w = fmaf(m[k][3], y[k].w, acc.w);
        }
        nfloat4 nv = { acc.x, acc.y, acc.z, acc.w };
        __builtin_nontemporal_store(nv, (nfloat4*)&op[(size_t)i * C4_]);
    }
}

extern "C" void kernel_launch(void* const* d_in, const int* in_sizes, int n_in,
                              void* d_out, int out_size, void* d_ws, size_t ws_size,
                              hipStream_t stream) {
    const float* x           = (const float*)d_in[0];
    const float* logit_alpha = (const float*)d_in[1];
    const float* mix_logits  = (const float*)d_in[2];
    float* out = (float*)d_out;
    float* ws  = (float*)d_ws;

    if (ws_size >= WS_NEEDED_BYTES) {
        // zero ticket counter + flags (first 64 KiB of ws)
        hipMemsetAsync(ws, 0, 65536, stream);
        ema_lookback<<<B_ * NTL, 512, LL * C_ * 4 + 16, stream>>>(
            x, logit_alpha, mix_logits, ws, out);
    } else {
        ema_pass1<<<B_ * NT_ / 2, 256, 0, stream>>>((const float4*)x, logit_alpha,
                                                    (float4*)ws);
        ema_pass2<<<B_ * K_ * 4, 128, 0, stream>>>(x, logit_alpha, ws);
        ema_pass3<<<B_ * NT_ / 2, 256, 0, stream>>>((const float4*)x, logit_alpha,
                                                    (const float4*)mix_logits,
                                                    (const float4*)ws, (float4*)out);
    }
}

// Round 5
// 82.392 us; speedup vs baseline: 14.4890x; 14.4890x over previous
//
#include <hip/hip_runtime.h>

// Problem constants (from reference setup_inputs)
#define B_  16
#define T_  4096
#define C_  512
#define K_  4
#define NT_ 64              // chunks along T
#define L_  (T_ / NT_)      // 64 steps per chunk
#define C4_ (C_ / 4)        // 128 float4 lanes per row

// ws layout (bf16-staging path):
//   bytes [0, 64Mi):   bf16 copy of x, same [b,t,c] layout (ushort)
//   bytes [64Mi, 72Mi): f32 chunk partials ws[((b*K+k)*NT+j)*C + c]
#define WS_BF16_BYTES  ((size_t)B_ * T_ * C_ * 2)          // 64 MiB
#define WS_PART_FLTS   (WS_BF16_BYTES / 4)                  // float offset of partials
#define WS_NEEDED      (WS_BF16_BYTES + (size_t)B_ * K_ * NT_ * C_ * 4)

typedef float  nfloat4  __attribute__((ext_vector_type(4)));
typedef unsigned short nushort4 __attribute__((ext_vector_type(4)));

__device__ __forceinline__ float sigmoid_clamp(float la) {
    float av = 1.0f / (1.0f + expf(-la));
    return fminf(fmaxf(av, 1e-4f), 1.0f - 1e-4f);
}

__device__ __forceinline__ unsigned short f32_to_bf16_rne(float f) {
    unsigned int u = __float_as_uint(f);
    u += 0x7fffu + ((u >> 16) & 1u);     // round-to-nearest-even
    return (unsigned short)(u >> 16);
}
__device__ __forceinline__ float bf16_to_f32(unsigned short h) {
    return __uint_as_float(((unsigned int)h) << 16);
}

// ======================================================================
// Pass 1: per (b, chunk j, c4): zero-init partial scans s_k(j) (f32),
// plus write bf16 copy of the x chunk into ws. Nontemporal x loads.
// ======================================================================
__global__ __launch_bounds__(256) void ema_pass1(const float4* __restrict__ x4,
                                                 const float* __restrict__ logit_alpha,
                                                 float* __restrict__ ws) {
    const int c4 = threadIdx.x & (C4_ - 1);
    const int jh = threadIdx.x >> 7;                 // two chunks per block
    const int b  = blockIdx.x / (NT_ / 2);
    const int j  = (blockIdx.x % (NT_ / 2)) * 2 + jh;

    float4 a[K_], oma[K_], s[K_];
#pragma unroll
    for (int k = 0; k < K_; ++k) {
        float4 la = ((const float4*)logit_alpha)[k * C4_ + c4];
        a[k].x = sigmoid_clamp(la.x); a[k].y = sigmoid_clamp(la.y);
        a[k].z = sigmoid_clamp(la.z); a[k].w = sigmoid_clamp(la.w);
        oma[k].x = 1.0f - a[k].x; oma[k].y = 1.0f - a[k].y;
        oma[k].z = 1.0f - a[k].z; oma[k].w = 1.0f - a[k].w;
        s[k].x = s[k].y = s[k].z = s[k].w = 0.0f;
    }

    const nfloat4* xp = (const nfloat4*)x4 + ((size_t)b * T_ + (size_t)j * L_) * C4_ + c4;
    nushort4* bp = (nushort4*)ws + ((size_t)b * T_ + (size_t)j * L_) * C4_ + c4;
#pragma unroll 4
    for (int i = 0; i < L_; ++i) {
        nfloat4 xv = __builtin_nontemporal_load(&xp[(size_t)i * C4_]);
        nushort4 hb = { f32_to_bf16_rne(xv.x), f32_to_bf16_rne(xv.y),
                        f32_to_bf16_rne(xv.z), f32_to_bf16_rne(xv.w) };
        bp[(size_t)i * C4_] = hb;
#pragma unroll
        for (int k = 0; k < K_; ++k) {
            s[k].x = fmaf(a[k].x, s[k].x, oma[k].x * xv.x);
            s[k].y = fmaf(a[k].y, s[k].y, oma[k].y * xv.y);
            s[k].z = fmaf(a[k].z, s[k].z, oma[k].z * xv.z);
            s[k].w = fmaf(a[k].w, s[k].w, oma[k].w * xv.w);
        }
    }

    float4* ws4 = (float4*)(ws + WS_PART_FLTS);
#pragma unroll
    for (int k = 0; k < K_; ++k)
        ws4[(((size_t)b * K_ + k) * NT_ + j) * C4_ + c4] = s[k];
}

// ======================================================================
// Pass 2: per (b, k, c): combine chunk partials into carries, in place.
// carry(0) = x[b,0,c]; ws[j] := carry INTO chunk j. 256 blocks.
// ======================================================================
__global__ __launch_bounds__(128) void ema_pass2(const float* __restrict__ x,
                                                 const float* __restrict__ logit_alpha,
                                                 float* __restrict__ wsp) {
    const int ct = blockIdx.x & 3;                   // c tile 0..3
    const int bk = blockIdx.x >> 2;
    const int b  = bk / K_;
    const int k  = bk % K_;
    const int c  = ct * 128 + threadIdx.x;

    float av = sigmoid_clamp(logit_alpha[k * C_ + c]);
    float A = av;                                    // A = a^64
#pragma unroll
    for (int q = 0; q < 6; ++q) A *= A;

    float carry = x[(size_t)b * T_ * C_ + c];        // seed: y[-1] := x[b,0,c]
    float* wsb = wsp + ((size_t)b * K_ + k) * NT_ * C_ + c;
    for (int j = 0; j < NT_; ++j) {
        float sj = wsb[(size_t)j * C_];
        wsb[(size_t)j * C_] = carry;
        carry = fmaf(A, carry, sj);
    }
}

// ======================================================================
// Pass 3: rescan each chunk from its carry using the L3-hot bf16 x copy,
// apply softmax mix, nontemporal f32 stores.
// ======================================================================
__global__ __launch_bounds__(256) void ema_pass3(const float* __restrict__ ws,
                                                 const float* __restrict__ logit_alpha,
                                                 const float4* __restrict__ ml4,
                                                 float4* __restrict__ out4) {
    const int c4 = threadIdx.x & (C4_ - 1);
    const int jh = threadIdx.x >> 7;
    const int b  = blockIdx.x / (NT_ / 2);
    const int j  = (blockIdx.x % (NT_ / 2)) * 2 + jh;

    float4 a[K_], oma[K_], y[K_];
    float  m[K_][4];
    const float4* ws4 = (const float4*)(ws + WS_PART_FLTS);
#pragma unroll
    for (int k = 0; k < K_; ++k) {
        float4 la = ((const float4*)logit_alpha)[k * C4_ + c4];
        a[k].x = sigmoid_clamp(la.x); a[k].y = sigmoid_clamp(la.y);
        a[k].z = sigmoid_clamp(la.z); a[k].w = sigmoid_clamp(la.w);
        oma[k].x = 1.0f - a[k].x; oma[k].y = 1.0f - a[k].y;
        oma[k].z = 1.0f - a[k].z; oma[k].w = 1.0f - a[k].w;
        y[k] = ws4[(((size_t)b * K_ + k) * NT_ + j) * C4_ + c4];
    }

    // softmax over mix_logits[c][0..K): one float4 per channel
#pragma unroll
    for (int ci = 0; ci < 4; ++ci) {
        float4 ml = ml4[(size_t)c4 * 4 + ci];
        float mx = fmaxf(fmaxf(ml.x, ml.y), fmaxf(ml.z, ml.w));
        float e0 = expf(ml.x - mx), e1 = expf(ml.y - mx);
        float e2 = expf(ml.z - mx), e3 = expf(ml.w - mx);
        float inv = 1.0f / (e0 + e1 + e2 + e3);
        m[0][ci] = e0 * inv; m[1][ci] = e1 * inv;
        m[2][ci] = e2 * inv; m[3][ci] = e3 * inv;
    }

    const nushort4* bp = (const nushort4*)ws + ((size_t)b * T_ + (size_t)j * L_) * C4_ + c4;
    float4*         op = out4 + ((size_t)b * T_ + (size_t)j * L_) * C4_ + c4;
#pragma unroll 4
    for (int i = 0; i < L_; ++i) {
        nushort4 hb = bp[(size_t)i * C4_];
        float xx = bf16_to_f32(hb.x), xy = bf16_to_f32(hb.y);
        float xz = bf16_to_f32(hb.z), xw = bf16_to_f32(hb.w);
        float4 acc; acc.x = acc.y = acc.z = acc.w = 0.0f;
#pragma unroll
        for (int k = 0; k < K_; ++k) {
            y[k].x = fmaf(a[k].x, y[k].x, oma[k].x * xx);
            y[k].y = fmaf(a[k].y, y[k].y, oma[k].y * xy);
            y[k].z = fmaf(a[k].z, y[k].z, oma[k].z * xz);
            y[k].w = fmaf(a[k].w, y[k].w, oma[k].w * xw);
            acc.x = fmaf(m[k][0], y[k].x, acc.x);
            acc.y = fmaf(m[k][1], y[k].y, acc.y);
            acc.z = fmaf(m[k][2], y[k].z, acc.z);
            acc.w = fmaf(m[k][3], y[k].w, acc.w);
        }
        nfloat4 nv = { acc.x, acc.y, acc.z, acc.w };
        __builtin_nontemporal_store(nv, (nfloat4*)&op[(size_t)i * C4_]);
    }
}

// ======================================================================
// Fallback 3-pass, pure f32 (proven R1 path) — used if ws too small.
// ======================================================================
__global__ __launch_bounds__(256) void ema_pass1_f32(const float4* __restrict__ x4,
                                                     const float* __restrict__ logit_alpha,
                                                     float4* __restrict__ ws4) {
    const int c4 = threadIdx.x & (C4_ - 1);
    const int jh = threadIdx.x >> 7;
    const int b  = blockIdx.x / (NT_ / 2);
    const int j  = (blockIdx.x % (NT_ / 2)) * 2 + jh;

    float4 a[K_], oma[K_], s[K_];
#pragma unroll
    for (int k = 0; k < K_; ++k) {
        float4 la = ((const float4*)logit_alpha)[k * C4_ + c4];
        a[k].x = sigmoid_clamp(la.x); a[k].y = sigmoid_clamp(la.y);
        a[k].z = sigmoid_clamp(la.z); a[k].w = sigmoid_clamp(la.w);
        oma[k].x = 1.0f - a[k].x; oma[k].y = 1.0f - a[k].y;
        oma[k].z = 1.0f - a[k].z; oma[k].w = 1.0f - a[k].w;
        s[k].x = s[k].y = s[k].z = s[k].w = 0.0f;
    }
    const float4* xp = x4 + ((size_t)b * T_ + (size_t)j * L_) * C4_ + c4;
#pragma unroll 4
    for (int i = 0; i < L_; ++i) {
        float4 xv = xp[(size_t)i * C4_];
#pragma unroll
        for (int k = 0; k < K_; ++k) {
            s[k].x = fmaf(a[k].x, s[k].x, oma[k].x * xv.x);
            s[k].y = fmaf(a[k].y, s[k].y, oma[k].y * xv.y);
            s[k].z = fmaf(a[k].z, s[k].z, oma[k].z * xv.z);
            s[k].w = fmaf(a[k].w, s[k].w, oma[k].w * xv.w);
        }
    }
#pragma unroll
    for (int k = 0; k < K_; ++k)
        ws4[(((size_t)b * K_ + k) * NT_ + j) * C4_ + c4] = s[k];
}

__global__ __launch_bounds__(256) void ema_pass3_f32(const float4* __restrict__ x4,
                                                     const float* __restrict__ logit_alpha,
                                                     const float4* __restrict__ ml4,
                                                     const float4* __restrict__ ws4,
                                                     float4* __restrict__ out4) {
    const int c4 = threadIdx.x & (C4_ - 1);
    const int jh = threadIdx.x >> 7;
    const int b  = blockIdx.x / (NT_ / 2);
    const int j  = (blockIdx.x % (NT_ / 2)) * 2 + jh;

    float4 a[K_], oma[K_], y[K_];
    float  m[K_][4];
#pragma unroll
    for (int k = 0; k < K_; ++k) {
        float4 la = ((const float4*)logit_alpha)[k * C4_ + c4];
        a[k].x = sigmoid_clamp(la.x); a[k].y = sigmoid_clamp(la.y);
        a[k].z = sigmoid_clamp(la.z); a[k].w = sigmoid_clamp(la.w);
        oma[k].x = 1.0f - a[k].x; oma[k].y = 1.0f - a[k].y;
        oma[k].z = 1.0f - a[k].z; oma[k].w = 1.0f - a[k].w;
        y[k] = ws4[(((size_t)b * K_ + k) * NT_ + j) * C4_ + c4];
    }
#pragma unroll
    for (int ci = 0; ci < 4; ++ci) {
        float4 ml = ml4[(size_t)c4 * 4 + ci];
        float mx = fmaxf(fmaxf(ml.x, ml.y), fmaxf(ml.z, ml.w));
        float e0 = expf(ml.x - mx), e1 = expf(ml.y - mx);
        float e2 = expf(ml.z - mx), e3 = expf(ml.w - mx);
        float inv = 1.0f / (e0 + e1 + e2 + e3);
        m[0][ci] = e0 * inv; m[1][ci] = e1 * inv;
        m[2][ci] = e2 * inv; m[3][ci] = e3 * inv;
    }
    const float4* xp = x4   + ((size_t)b * T_ + (size_t)j * L_) * C4_ + c4;
    float4*       op = out4 + ((size_t)b * T_ + (size_t)j * L_) * C4_ + c4;
#pragma unroll 4
    for (int i = 0; i < L_; ++i) {
        float4 xv = xp[(size_t)i * C4_];
        float4 acc; acc.x = acc.y = acc.z = acc.w = 0.0f;
#pragma unroll
        for (int k = 0; k < K_; ++k) {
            y[k].x = fmaf(a[k].x, y[k].x, oma[k].x * xv.x);
            y[k].y = fmaf(a[k].y, y[k].y, oma[k].y * xv.y);
            y[k].z = fmaf(a[k].z, y[k].z, oma[k].z * xv.z);
            y[k].w = fmaf(a[k].w, y[k].w, oma[k].w * xv.w);
            acc.x = fmaf(m[k][0], y[k].x, acc.x);
            acc.y = fmaf(m[k][1], y[k].y, acc.y);
            acc.z = fmaf(m[k][2], y[k].z, acc.z);
            acc.w = fmaf(m[k][3], y[k].w, acc.w);
        }
        nfloat4 nv = { acc.x, acc.y, acc.z, acc.w };
        __builtin_nontemporal_store(nv, (nfloat4*)&op[(size_t)i * C4_]);
    }
}

extern "C" void kernel_launch(void* const* d_in, const int* in_sizes, int n_in,
                              void* d_out, int out_size, void* d_ws, size_t ws_size,
                              hipStream_t stream) {
    const float* x           = (const float*)d_in[0];
    const float* logit_alpha = (const float*)d_in[1];
    const float* mix_logits  = (const float*)d_in[2];
    float* out = (float*)d_out;
    float* ws  = (float*)d_ws;

    if (ws_size >= WS_NEEDED) {
        ema_pass1<<<B_ * NT_ / 2, 256, 0, stream>>>((const float4*)x, logit_alpha, ws);
        ema_pass2<<<B_ * K_ * 4, 128, 0, stream>>>(x, logit_alpha, ws + WS_PART_FLTS);
        ema_pass3<<<B_ * NT_ / 2, 256, 0, stream>>>(ws, logit_alpha,
                                                    (const float4*)mix_logits,
                                                    (float4*)out);
    } else {
        ema_pass1_f32<<<B_ * NT_ / 2, 256, 0, stream>>>((const float4*)x, logit_alpha,
                                                        (float4*)ws);
        ema_pass2<<<B_ * K_ * 4, 128, 0, stream>>>(x, logit_alpha, ws);
        ema_pass3_f32<<<B_ * NT_ / 2, 256, 0, stream>>>((const float4*)x, logit_alpha,
                                                        (const float4*)mix_logits,
                                                        (const float4*)ws, (float4*)out);
    }
}